// Round 10
// baseline (170.452 us; speedup 1.0000x reference)
//
#include <hip/hip_runtime.h>
#include <stdint.h>

#define BATCH 16384
#define MAXA 32
#define FEAT 768
#define HIDDEN 1024

#define KC 24                    // K-chunks of 32 features
#define NTH 16                   // N-tiles per block (one 512-h half)
#define BTILE (KC * 1024)        // 24576 B per N-tile slab
#define ASTRIDE 784              // prep LDS row stride

typedef int v4i  __attribute__((ext_vector_type(4)));
typedef int v16i __attribute__((ext_vector_type(16)));

// ---------------------------------------------------------------------------
// Prep: per-h absmax -> scale; quantize SIGNED i8 (-127..127); write directly
// in MFMA B-fragment order:  byte(f,h) -> Bf[(nt*KC+kc)*1024 + l*16 + e]
// where nt=h>>5, kc=f>>5, l=((f>>4)&1)<<5 | (h&31), e=f&15.  (R8/R9-verified)
// Also zeroes the output accumulator (nn_mfma atomicAdds into d_out).
// ---------------------------------------------------------------------------
__global__ __launch_bounds__(256) void prep_quant(const float* __restrict__ ftw,
                                                  uint8_t* __restrict__ Bf,
                                                  float* __restrict__ scale,
                                                  float* __restrict__ outz) {
  const int h0 = blockIdx.x * 8;
  const int hloc = threadIdx.x >> 5;   // 0..7
  const int l32 = threadIdx.x & 31;    // 0..31
  const int h = h0 + hloc;

  float w[24];
  float amax = 0.f;
  const float* __restrict__ src = ftw + (size_t)h * FEAT;
#pragma unroll
  for (int k = 0; k < 24; ++k) {
    w[k] = src[l32 + 32 * k];
    amax = fmaxf(amax, fabsf(w[k]));
  }
#pragma unroll
  for (int m = 1; m <= 16; m <<= 1)
    amax = fmaxf(amax, __shfl_xor(amax, m, 64));
  amax = fmaxf(amax, 1e-20f);
  if (l32 == 0) scale[h] = amax / 127.f;
  const float inv = 127.f / amax;

  __shared__ __align__(16) uint8_t tile[8][ASTRIDE];  // [hloc][f], 6.1 KB
#pragma unroll
  for (int k = 0; k < 24; ++k) {
    int q = __float2int_rn(w[k] * inv);               // [-127,127] signed
    tile[hloc][l32 + 32 * k] = (uint8_t)(int8_t)q;
  }
  __syncthreads();

  // scatter 16-byte groups into fragment order (16 consecutive f, same h)
  for (int g = threadIdx.x; g < 8 * 48; g += 256) {
    int hl = g / 48, fg = g % 48;
    int kc = fg >> 1, lh = fg & 1;
    int hh = h0 + hl;
    uint4 v = *(const uint4*)&tile[hl][fg * 16];
    size_t daddr = ((size_t)((hh >> 5) * KC + kc) << 10) +
                   (size_t)(((lh << 5) | (hh & 31)) << 4);
    *(uint4*)(Bf + daddr) = v;
  }

  if (threadIdx.x < 128)   // zero the per-row output accumulator (16384 f32)
    outz[blockIdx.x * 128 + threadIdx.x] = 0.f;
}

// ---------------------------------------------------------------------------
// Dense i8 MFMA v3. Grid 256 (1/CU), 512 threads = 8 waves = 2 waves/SIMD.
// Block = 128 rows x one 512-h N-half; wave = 32 rows x 1 side.
// Fixes R9's two exposed costs: (a) A-tile kept register-resident for real:
// built as a 768-bit row bitmap (atomicOr into 3 KB/wave LDS, dedupe free),
// one-time nibble-expand ((bits&0xF)*0x204081)&0x01010101 to areg[24] = 96
// VGPR (R9's areg[2][24]=192 forced scratch spill: VGPR=152 + 3.5 MB
// scratch reloads in-loop). (b) no LDS-B, no in-loop barriers: B fragments
// stream straight from global; the 24 KB slab is shared by 8 waves -> ~7/8
// L1 hits; 2 waves/SIMD + two interleaved MFMA chains hide latency.
// ---------------------------------------------------------------------------
__global__ __launch_bounds__(512, 2) void nn_mfma(
    const int* __restrict__ stm, const int* __restrict__ nstm,
    const uint8_t* __restrict__ Bf, const float* __restrict__ scale,
    const float* __restrict__ bias, const float* __restrict__ outw,
    float* __restrict__ outz)
{
  const int tid  = threadIdx.x;
  const int lane = tid & 63;
  const int wid  = tid >> 6;        // 0..7
  const int side = wid & 1;         // 0 = stm, 1 = nstm
  const int rgrp = wid >> 1;        // 0..3
  const int nh   = blockIdx.x & 1;  // N-half (h = nh*512 .. +512)
  const int R    = (blockIdx.x >> 1) * 128;
  const int l31  = lane & 31;
  const int lh   = lane >> 5;

  __shared__ uint32_t amap[8][32 * 24];   // 24576 B: per-wave row bitmaps
  __shared__ float    sbo[2048];          // 8 KB: scale|bias|outw (N-half)

  // ---- stage consts: 2048 f32 = 512 float4, one per thread
  {
    float4* d = (float4*)sbo;
    if (tid < 128)       d[tid] = ((const float4*)(scale + nh * 512))[tid];
    else if (tid < 256)  d[tid] = ((const float4*)(bias + nh * 512))[tid - 128];
    else if (tid < 384)  d[tid] = ((const float4*)(outw + nh * 512))[tid - 256];
    else                 d[tid] = ((const float4*)(outw + HIDDEN + nh * 512))[tid - 384];
  }

  // ---- zero this wave's bitmap (768 u32), then scatter-OR the indices.
  // Dups OR harmlessly (ref .at[].max() semantics); idx<0 skipped.
  uint32_t* mp = amap[wid];
  {
    const uint4 z = {0u, 0u, 0u, 0u};
    ((uint4*)mp)[lane] = z;
    ((uint4*)mp)[64 + lane] = z;
    ((uint4*)mp)[128 + lane] = z;
  }
  const int* __restrict__ isrc = side ? nstm : stm;
#pragma unroll
  for (int i = 0; i < 16; ++i) {
    int row = 2 * i + lh;
    int idx = isrc[(R + rgrp * 32 + row) * MAXA + l31];
    if (idx >= 0) atomicOr(&mp[row * 24 + (idx >> 5)], 1u << (idx & 31));
  }
  __syncthreads();

  // ---- lift: lane (m=l31, lh) expands its 16-bit half of each k-word into
  // a 16-byte 0/1 fragment. areg[kc][j] byte e = bit (4j+e) of the half.
  v4i areg[KC];
#pragma unroll
  for (int kc = 0; kc < KC; ++kc) {
    uint32_t wbits = mp[l31 * 24 + kc];
    uint32_t hbits = (wbits >> (lh * 16)) & 0xFFFFu;
    v4i a;
#pragma unroll
    for (int j = 0; j < 4; ++j)
      a[j] = (int)((((hbits >> (4 * j)) & 0xFu) * 0x00204081u) & 0x01010101u);
    areg[kc] = a;
  }

  float prow[16];
#pragma unroll
  for (int r = 0; r < 16; ++r) prow[r] = 0.f;

  const uint8_t* __restrict__ Bbase =
      Bf + (size_t)(nh * NTH) * BTILE + (size_t)lane * 16;

#pragma unroll 1
  for (int nt = 0; nt < NTH; ++nt) {
    const uint8_t* bp = Bbase + (size_t)nt * BTILE;
    v16i acc0, acc1;
#pragma unroll
    for (int r = 0; r < 16; ++r) { acc0[r] = 0; acc1[r] = 0; }
    // two interleaved K-chains (even/odd kc): 2x dep spacing, exact i32 sum
#pragma unroll
    for (int kc = 0; kc < KC; kc += 2) {
      v4i b0 = *(const v4i*)(bp + (size_t)kc * 1024);
      v4i b1 = *(const v4i*)(bp + (size_t)kc * 1024 + 1024);
      acc0 = __builtin_amdgcn_mfma_i32_32x32x32_i8(areg[kc], b0, acc0, 0, 0, 0);
      acc1 = __builtin_amdgcn_mfma_i32_32x32x32_i8(areg[kc + 1], b1, acc1, 0, 0, 0);
    }
    // epilogue: h = nh*512 + nt*32 + l31 (C col = lane&31)
    float s  = sbo[nt * 32 + l31];
    float bb = sbo[512 + nt * 32 + l31];
    float o  = sbo[1024 + side * 512 + nt * 32 + l31];
#pragma unroll
    for (int r = 0; r < 16; ++r) {
      int q = acc0[r] + acc1[r];
      float hv = fminf(fmaxf(fmaf((float)q, s, bb), 0.f), 1.f);
      prow[r] = fmaf(hv, o, prow[r]);
    }
  }

  // ---- reduce over the 32 h-columns (stay within each 32-lane half)
#pragma unroll
  for (int off = 16; off >= 1; off >>= 1)
#pragma unroll
    for (int r = 0; r < 16; ++r) prow[r] += __shfl_xor(prow[r], off, 64);

  if (l31 == 0) {
    // C row = (reg&3) + 8*(reg>>2) + 4*(lane>>5)  [HW-verified 32x32 layout]
#pragma unroll
    for (int r = 0; r < 16; ++r) {
      int crow = (r & 3) + 8 * (r >> 2) + 4 * lh;
      atomicAdd(&outz[R + rgrp * 32 + crow], prow[r]);
    }
  }
}

// ---------------------------------------------------------------------------
// Final: sigmoid in place over the accumulated per-row dot.
// ---------------------------------------------------------------------------
__global__ __launch_bounds__(256) void nn_finish(float* __restrict__ outz,
                                                 const float* __restrict__ outb) {
  const int i = blockIdx.x * 256 + threadIdx.x;
  float y = outz[i] + outb[0];
  outz[i] = 1.f / (1.f + __expf(-y));
}

extern "C" void kernel_launch(void* const* d_in, const int* in_sizes, int n_in,
                              void* d_out, int out_size, void* d_ws, size_t ws_size,
                              hipStream_t stream) {
  const int*   stm  = (const int*)d_in[0];
  const int*   nstm = (const int*)d_in[1];
  const float* ftw  = (const float*)d_in[2];   // (1024, 768) fp32
  const float* ftb  = (const float*)d_in[3];   // (1024,) fp32
  const float* outw = (const float*)d_in[4];   // (2048,) fp32
  const float* outb = (const float*)d_in[5];   // (1,) fp32

  uint8_t* Bf    = (uint8_t*)d_ws;                        // 768 KiB fragments
  float*   scale = (float*)(Bf + (size_t)FEAT * HIDDEN);  // 4 KB
  float*   outz  = (float*)d_out;                         // accumulator + output

  prep_quant<<<HIDDEN / 8, 256, 0, stream>>>(ftw, Bf, scale, outz);
  nn_mfma<<<(BATCH / 128) * 2, 512, 0, stream>>>(stm, nstm, Bf, scale, ftb,
                                                 outw, outz);
  nn_finish<<<BATCH / 256, 256, 0, stream>>>(outz, outb);
}

// Round 13
// 115.208 us; speedup vs baseline: 1.4795x; 1.4795x over previous
//
#include <hip/hip_runtime.h>
#include <stdint.h>

#define BATCH 16384
#define MAXA 32
#define FEAT 768
#define HIDDEN 1024

typedef unsigned int u32x4 __attribute__((ext_vector_type(4)));

// ---------------------------------------------------------------------------
// Fused prep (R7-verified): per-h absmax -> scale; quantize u8 biased +128;
// transpose through LDS tile; wQ[f][h], plus dummy zero row f=768 (0x80).
// ---------------------------------------------------------------------------
__global__ __launch_bounds__(256) void prep_quant(const float* __restrict__ ftw,
                                                  uint8_t* __restrict__ wQ,
                                                  float* __restrict__ scale) {
  const int h0 = blockIdx.x * 8;
  const int hloc = threadIdx.x >> 5;   // 0..7
  const int l32 = threadIdx.x & 31;    // 0..31
  const int h = h0 + hloc;

  float w[24];
  float amax = 0.f;
  const float* __restrict__ src = ftw + (size_t)h * FEAT;
#pragma unroll
  for (int k = 0; k < 24; ++k) {
    w[k] = src[l32 + 32 * k];
    amax = fmaxf(amax, fabsf(w[k]));
  }
#pragma unroll
  for (int m = 1; m <= 16; m <<= 1)
    amax = fmaxf(amax, __shfl_xor(amax, m, 64));
  amax = fmaxf(amax, 1e-20f);
  if (l32 == 0) scale[h] = amax / 127.f;
  const float inv = 127.f / amax;

  __shared__ __align__(16) uint8_t tile[FEAT * 8];  // [f][hloc], 6 KB
#pragma unroll
  for (int k = 0; k < 24; ++k) {
    int q = __float2int_rn(w[k] * inv);             // [-127,127]
    tile[(l32 + 32 * k) * 8 + hloc] = (uint8_t)(q + 128);
  }
  __syncthreads();

#pragma unroll
  for (int p = 0; p < 3; ++p) {
    int f = threadIdx.x + 256 * p;
    unsigned long long v = *(const unsigned long long*)&tile[f * 8];
    *(unsigned long long*)(wQ + (size_t)f * HIDDEN + h0) = v;
  }

  if (blockIdx.x == 0)   // dummy zero column f=768 (biased 0x80), 1024 B
    ((uint32_t*)(wQ + (size_t)FEAT * HIDDEN))[threadIdx.x] = 0x80808080u;
}

// unpack a u32 (4 u8, h-consecutive) into two u16-pairs and accumulate.
// Plain u32 add == packed u16 add: field max = 32*255 = 8160, never carries.
__device__ __forceinline__ void acc16(uint32_t* acc, u32x4 w) {
  acc[0] += __builtin_amdgcn_perm(0u, w.x, 0x0c010c00u);
  acc[1] += __builtin_amdgcn_perm(0u, w.x, 0x0c030c02u);
  acc[2] += __builtin_amdgcn_perm(0u, w.y, 0x0c010c00u);
  acc[3] += __builtin_amdgcn_perm(0u, w.y, 0x0c030c02u);
  acc[4] += __builtin_amdgcn_perm(0u, w.z, 0x0c010c00u);
  acc[5] += __builtin_amdgcn_perm(0u, w.z, 0x0c030c02u);
  acc[6] += __builtin_amdgcn_perm(0u, w.w, 0x0c010c00u);
  acc[7] += __builtin_amdgcn_perm(0u, w.w, 0x0c030c02u);
}

// dequant one u16 field + bias + clip01
__device__ __forceinline__ float dq(uint32_t a, int hi, float s, float b) {
  int q = (int)(hi ? (a >> 16) : (a & 0xffffu)) - 32 * 128;
  return fminf(fmaxf(fmaf((float)q, s, b), 0.f), 1.f);
}

// ---------------------------------------------------------------------------
// R7 structure (verified 52us) + NON-TEMPORAL gather loads. Theory: all
// three gather schedules (R1/R4/R7) pin at 17-18.5 TB/s regardless of
// concurrency -> the cap is L1 miss-allocation in TCP (random 1KB rows,
// 769 KB working set, ~0% L1 hits), ~32 B/cy/CU. nt loads skip L1
// allocation; if that's the cap this streams closer to line rate. Numerics
// are bit-identical to R7 (only the cache policy bit changes).
// ---------------------------------------------------------------------------
__global__ __launch_bounds__(256) void nn_fwd(
    const int* __restrict__ stm, const int* __restrict__ nstm,
    const uint8_t* __restrict__ wQ, const float* __restrict__ scale,
    const float* __restrict__ bias, const float* __restrict__ outw,
    const float* __restrict__ outb, float* __restrict__ out)
{
  const int lane = threadIdx.x & 63;
  const int wid  = threadIdx.x >> 6;       // 0..3
  const int rowA = blockIdx.x * 8 + wid * 2;
  const int rowB = rowA + 1;
  const int half = lane >> 5;              // 0 = stm, 1 = nstm
  const int pos  = lane & 31;

  const int* __restrict__ src = half ? nstm : stm;
  int idxA = src[rowA * MAXA + pos];       // lanes 0-31: stm, 32-63: nstm
  int idxB = src[rowB * MAXA + pos];
  bool vA = idxA >= 0, vB = idxB >= 0;     // -1 padding -> no contribution
  // dedupe within each half: reference .at[].max() counts duplicates once
#pragma unroll
  for (int j = 0; j < 31; ++j) {
    int oA = __shfl(idxA, (half << 5) | j, 64);
    int oB = __shfl(idxB, (half << 5) | j, 64);
    if (j < pos && oA == idxA) vA = false;
    if (j < pos && oB == idxB) vB = false;
  }
  const int fmA = vA ? idxA : FEAT;        // dummy zero column
  const int fmB = vB ? idxB : FEAT;

  uint32_t aAs[8], aAn[8], aBs[8], aBn[8];
#pragma unroll
  for (int k = 0; k < 8; ++k) { aAs[k] = 0u; aAn[k] = 0u; aBs[k] = 0u; aBn[k] = 0u; }

  // 32 iters x 4 streams; column bases are wave-uniform (readlane -> SGPR)
  // so each is a saddr-form global_load_dwordx4 with the nt policy bit.
#pragma unroll
  for (int j = 0; j < 32; ++j) {
    int fAs = __builtin_amdgcn_readlane(fmA, j);
    int fAn = __builtin_amdgcn_readlane(fmA, 32 + j);
    int fBs = __builtin_amdgcn_readlane(fmB, j);
    int fBn = __builtin_amdgcn_readlane(fmB, 32 + j);
    u32x4 wAs = __builtin_nontemporal_load(((const u32x4*)(wQ + (size_t)fAs * HIDDEN)) + lane);
    u32x4 wAn = __builtin_nontemporal_load(((const u32x4*)(wQ + (size_t)fAn * HIDDEN)) + lane);
    u32x4 wBs = __builtin_nontemporal_load(((const u32x4*)(wQ + (size_t)fBs * HIDDEN)) + lane);
    u32x4 wBn = __builtin_nontemporal_load(((const u32x4*)(wQ + (size_t)fBn * HIDDEN)) + lane);
    acc16(aAs, wAs);
    acc16(aAn, wAn);
    acc16(aBs, wBs);
    acc16(aBn, wBn);
  }

  // Epilogue: dequant + bias + clip01, fused 2048-dot with out_w, sigmoid.
  const int hbase = lane * 16;
  const float4* s4 = (const float4*)(scale + hbase);
  const float4* b4 = (const float4*)(bias + hbase);
  const float4* oS4 = (const float4*)(outw + hbase);
  const float4* oN4 = (const float4*)(outw + HIDDEN + hbase);
  float pA = 0.f, pB = 0.f;
#pragma unroll
  for (int q = 0; q < 4; ++q) {
    float4 s = s4[q], b = b4[q], oS = oS4[q], oN = oN4[q];
    uint32_t a0, a1;
    a0 = aAs[2 * q]; a1 = aAs[2 * q + 1];
    pA += dq(a0, 0, s.x, b.x) * oS.x + dq(a0, 1, s.y, b.y) * oS.y +
          dq(a1, 0, s.z, b.z) * oS.z + dq(a1, 1, s.w, b.w) * oS.w;
    a0 = aAn[2 * q]; a1 = aAn[2 * q + 1];
    pA += dq(a0, 0, s.x, b.x) * oN.x + dq(a0, 1, s.y, b.y) * oN.y +
          dq(a1, 0, s.z, b.z) * oN.z + dq(a1, 1, s.w, b.w) * oN.w;
    a0 = aBs[2 * q]; a1 = aBs[2 * q + 1];
    pB += dq(a0, 0, s.x, b.x) * oS.x + dq(a0, 1, s.y, b.y) * oS.y +
          dq(a1, 0, s.z, b.z) * oS.z + dq(a1, 1, s.w, b.w) * oS.w;
    a0 = aBn[2 * q]; a1 = aBn[2 * q + 1];
    pB += dq(a0, 0, s.x, b.x) * oN.x + dq(a0, 1, s.y, b.y) * oN.y +
          dq(a1, 0, s.z, b.z) * oN.z + dq(a1, 1, s.w, b.w) * oN.w;
  }
#pragma unroll
  for (int off = 32; off > 0; off >>= 1) {
    pA += __shfl_down(pA, off, 64);
    pB += __shfl_down(pB, off, 64);
  }
  if (lane == 0) {
    const float ob = outb[0];
    out[rowA] = 1.f / (1.f + __expf(-(pA + ob)));
    out[rowB] = 1.f / (1.f + __expf(-(pB + ob)));
  }
}

extern "C" void kernel_launch(void* const* d_in, const int* in_sizes, int n_in,
                              void* d_out, int out_size, void* d_ws, size_t ws_size,
                              hipStream_t stream) {
  const int*   stm  = (const int*)d_in[0];
  const int*   nstm = (const int*)d_in[1];
  const float* ftw  = (const float*)d_in[2];   // (1024, 768) fp32
  const float* ftb  = (const float*)d_in[3];   // (1024,) fp32
  const float* outw = (const float*)d_in[4];   // (2048,) fp32
  const float* outb = (const float*)d_in[5];   // (1,) fp32

  uint8_t* wQ    = (uint8_t*)d_ws;                               // 769*1024 B
  float*   scale = (float*)(wQ + (size_t)(FEAT + 1) * HIDDEN);   // 4 KB

  prep_quant<<<HIDDEN / 8, 256, 0, stream>>>(ftw, wQ, scale);
  nn_fwd<<<BATCH / 8, 256, 0, stream>>>(stm, nstm, wQ, scale, ftb, outw, outb,
                                        (float*)d_out);
}

// Round 14
// 112.325 us; speedup vs baseline: 1.5175x; 1.0257x over previous
//
#include <hip/hip_runtime.h>
#include <stdint.h>

#define BATCH 16384
#define MAXA 32
#define FEAT 768
#define HIDDEN 1024

// ---------------------------------------------------------------------------
// Fused prep (R7-verified): per-h absmax -> scale; quantize u8 biased +128;
// transpose through LDS tile; wQ[f][h], plus dummy zero row f=768 (0x80).
// ---------------------------------------------------------------------------
__global__ __launch_bounds__(256) void prep_quant(const float* __restrict__ ftw,
                                                  uint8_t* __restrict__ wQ,
                                                  float* __restrict__ scale) {
  const int h0 = blockIdx.x * 8;
  const int hloc = threadIdx.x >> 5;   // 0..7
  const int l32 = threadIdx.x & 31;    // 0..31
  const int h = h0 + hloc;

  float w[24];
  float amax = 0.f;
  const float* __restrict__ src = ftw + (size_t)h * FEAT;
#pragma unroll
  for (int k = 0; k < 24; ++k) {
    w[k] = src[l32 + 32 * k];
    amax = fmaxf(amax, fabsf(w[k]));
  }
#pragma unroll
  for (int m = 1; m <= 16; m <<= 1)
    amax = fmaxf(amax, __shfl_xor(amax, m, 64));
  amax = fmaxf(amax, 1e-20f);
  if (l32 == 0) scale[h] = amax / 127.f;
  const float inv = 127.f / amax;

  __shared__ __align__(16) uint8_t tile[FEAT * 8];  // [f][hloc], 6 KB
#pragma unroll
  for (int k = 0; k < 24; ++k) {
    int q = __float2int_rn(w[k] * inv);             // [-127,127]
    tile[(l32 + 32 * k) * 8 + hloc] = (uint8_t)(q + 128);
  }
  __syncthreads();

#pragma unroll
  for (int p = 0; p < 3; ++p) {
    int f = threadIdx.x + 256 * p;
    unsigned long long v = *(const unsigned long long*)&tile[f * 8];
    *(unsigned long long*)(wQ + (size_t)f * HIDDEN + h0) = v;
  }

  if (blockIdx.x == 0)   // dummy zero column f=768 (biased 0x80), 1024 B
    ((uint32_t*)(wQ + (size_t)FEAT * HIDDEN))[threadIdx.x] = 0x80808080u;
}

// unpack a u32 (4 u8, h-consecutive) into two u16-pairs and accumulate.
// Plain u32 add == packed u16 add: field max = 32*255 = 8160, never carries.
__device__ __forceinline__ void acc16(uint32_t* acc, uint4 w) {
  acc[0] += __builtin_amdgcn_perm(0u, w.x, 0x0c010c00u);
  acc[1] += __builtin_amdgcn_perm(0u, w.x, 0x0c030c02u);
  acc[2] += __builtin_amdgcn_perm(0u, w.y, 0x0c010c00u);
  acc[3] += __builtin_amdgcn_perm(0u, w.y, 0x0c030c02u);
  acc[4] += __builtin_amdgcn_perm(0u, w.z, 0x0c010c00u);
  acc[5] += __builtin_amdgcn_perm(0u, w.z, 0x0c030c02u);
  acc[6] += __builtin_amdgcn_perm(0u, w.w, 0x0c010c00u);
  acc[7] += __builtin_amdgcn_perm(0u, w.w, 0x0c030c02u);
}

// dequant one u16 field + bias + clip01
__device__ __forceinline__ float dq(uint32_t a, int hi, float s, float b) {
  int q = (int)(hi ? (a >> 16) : (a & 0xffffu)) - 32 * 128;
  return fminf(fmaxf(fmaf((float)q, s, b), 0.f), 1.f);
}

// ---------------------------------------------------------------------------
// R7 (session best, verified 52.1us / total 113.2): one wave per TWO batch
// rows -> 4 independent gather streams (rowA/stm, rowA/nstm, rowB/stm,
// rowB/nstm). Wave-uniform column bases (readlane -> SGPR) give saddr-form
// global_load_dwordx4. This sits at the measured ~18.5 TB/s random-line
// L2->CU ceiling (R1/R4/R7/R13 all converge there); VALU floor ~17us is
// not binding. Normal (cached) loads: CU-local row reuse (~5 refs/CU/row)
// earns L1 hits that nt loads forfeited (R13: +3.4us).
// ---------------------------------------------------------------------------
__global__ __launch_bounds__(256) void nn_fwd(
    const int* __restrict__ stm, const int* __restrict__ nstm,
    const uint8_t* __restrict__ wQ, const float* __restrict__ scale,
    const float* __restrict__ bias, const float* __restrict__ outw,
    const float* __restrict__ outb, float* __restrict__ out)
{
  const int lane = threadIdx.x & 63;
  const int wid  = threadIdx.x >> 6;       // 0..3
  const int rowA = blockIdx.x * 8 + wid * 2;
  const int rowB = rowA + 1;
  const int half = lane >> 5;              // 0 = stm, 1 = nstm
  const int pos  = lane & 31;

  const int* __restrict__ src = half ? nstm : stm;
  int idxA = src[rowA * MAXA + pos];       // lanes 0-31: stm, 32-63: nstm
  int idxB = src[rowB * MAXA + pos];
  bool vA = idxA >= 0, vB = idxB >= 0;     // -1 padding -> no contribution
  // dedupe within each half: reference .at[].max() counts duplicates once
#pragma unroll
  for (int j = 0; j < 31; ++j) {
    int oA = __shfl(idxA, (half << 5) | j, 64);
    int oB = __shfl(idxB, (half << 5) | j, 64);
    if (j < pos && oA == idxA) vA = false;
    if (j < pos && oB == idxB) vB = false;
  }
  const int fmA = vA ? idxA : FEAT;        // dummy zero column
  const int fmB = vB ? idxB : FEAT;

  uint32_t aAs[8], aAn[8], aBs[8], aBn[8];
#pragma unroll
  for (int k = 0; k < 8; ++k) { aAs[k] = 0u; aAn[k] = 0u; aBs[k] = 0u; aBn[k] = 0u; }

  // 32 iters x 4 streams; column bases are wave-uniform (readlane -> SGPR)
  // so each is a saddr-form global_load_dwordx4. Natural vmcnt pipelining
  // keeps ~4 loads in flight per wave.
#pragma unroll
  for (int j = 0; j < 32; ++j) {
    int fAs = __builtin_amdgcn_readlane(fmA, j);
    int fAn = __builtin_amdgcn_readlane(fmA, 32 + j);
    int fBs = __builtin_amdgcn_readlane(fmB, j);
    int fBn = __builtin_amdgcn_readlane(fmB, 32 + j);
    uint4 wAs = ((const uint4*)(wQ + (size_t)fAs * HIDDEN))[lane];
    uint4 wAn = ((const uint4*)(wQ + (size_t)fAn * HIDDEN))[lane];
    uint4 wBs = ((const uint4*)(wQ + (size_t)fBs * HIDDEN))[lane];
    uint4 wBn = ((const uint4*)(wQ + (size_t)fBn * HIDDEN))[lane];
    acc16(aAs, wAs);
    acc16(aAn, wAn);
    acc16(aBs, wBs);
    acc16(aBn, wBn);
  }

  // Epilogue: dequant + bias + clip01, fused 2048-dot with out_w, sigmoid.
  const int hbase = lane * 16;
  const float4* s4 = (const float4*)(scale + hbase);
  const float4* b4 = (const float4*)(bias + hbase);
  const float4* oS4 = (const float4*)(outw + hbase);
  const float4* oN4 = (const float4*)(outw + HIDDEN + hbase);
  float pA = 0.f, pB = 0.f;
#pragma unroll
  for (int q = 0; q < 4; ++q) {
    float4 s = s4[q], b = b4[q], oS = oS4[q], oN = oN4[q];
    uint32_t a0, a1;
    a0 = aAs[2 * q]; a1 = aAs[2 * q + 1];
    pA += dq(a0, 0, s.x, b.x) * oS.x + dq(a0, 1, s.y, b.y) * oS.y +
          dq(a1, 0, s.z, b.z) * oS.z + dq(a1, 1, s.w, b.w) * oS.w;
    a0 = aAn[2 * q]; a1 = aAn[2 * q + 1];
    pA += dq(a0, 0, s.x, b.x) * oN.x + dq(a0, 1, s.y, b.y) * oN.y +
          dq(a1, 0, s.z, b.z) * oN.z + dq(a1, 1, s.w, b.w) * oN.w;
    a0 = aBs[2 * q]; a1 = aBs[2 * q + 1];
    pB += dq(a0, 0, s.x, b.x) * oS.x + dq(a0, 1, s.y, b.y) * oS.y +
          dq(a1, 0, s.z, b.z) * oS.z + dq(a1, 1, s.w, b.w) * oS.w;
    a0 = aBn[2 * q]; a1 = aBn[2 * q + 1];
    pB += dq(a0, 0, s.x, b.x) * oN.x + dq(a0, 1, s.y, b.y) * oN.y +
          dq(a1, 0, s.z, b.z) * oN.z + dq(a1, 1, s.w, b.w) * oN.w;
  }
#pragma unroll
  for (int off = 32; off > 0; off >>= 1) {
    pA += __shfl_down(pA, off, 64);
    pB += __shfl_down(pB, off, 64);
  }
  if (lane == 0) {
    const float ob = outb[0];
    out[rowA] = 1.f / (1.f + __expf(-(pA + ob)));
    out[rowB] = 1.f / (1.f + __expf(-(pB + ob)));
  }
}

extern "C" void kernel_launch(void* const* d_in, const int* in_sizes, int n_in,
                              void* d_out, int out_size, void* d_ws, size_t ws_size,
                              hipStream_t stream) {
  const int*   stm  = (const int*)d_in[0];
  const int*   nstm = (const int*)d_in[1];
  const float* ftw  = (const float*)d_in[2];   // (1024, 768) fp32
  const float* ftb  = (const float*)d_in[3];   // (1024,) fp32
  const float* outw = (const float*)d_in[4];   // (2048,) fp32
  const float* outb = (const float*)d_in[5];   // (1,) fp32

  uint8_t* wQ    = (uint8_t*)d_ws;                               // 769*1024 B
  float*   scale = (float*)(wQ + (size_t)(FEAT + 1) * HIDDEN);   // 4 KB

  prep_quant<<<HIDDEN / 8, 256, 0, stream>>>(ftw, wQ, scale);
  nn_fwd<<<BATCH / 8, 256, 0, stream>>>(stm, nstm, wQ, scale, ftb, outw, outb,
                                        (float*)d_out);
}